// Round 10
// baseline (499.717 us; speedup 1.0000x reference)
//
#include <hip/hip_runtime.h>
#include <hip/hip_bf16.h>
#include <math.h>

static __device__ __forceinline__ float sigm(float x) { return 1.0f / (1.0f + expf(-x)); }

// fp32 -> bf16 bits, round-to-nearest-even
static __device__ __forceinline__ short f2bf_s(float f) {
    unsigned u = __float_as_uint(f);
    u += 0x7fffu + ((u >> 16) & 1u);
    return (short)(u >> 16);
}
// bf16 bits -> fp32
static __device__ __forceinline__ float bfb2f(short s) {
    return __uint_as_float(((unsigned)(unsigned short)s) << 16);
}

typedef __attribute__((ext_vector_type(8))) short short8;
typedef __attribute__((ext_vector_type(4))) short short4v;
typedef __attribute__((ext_vector_type(4))) float f32x4;

// ---------------- fused prep: maps + prepw3 + prepw + prepx in one launch ----------------
// All four jobs are mutually independent AND write disjoint buffers. k_premult
// (needs om_bf) launches after.
// Block ranges: [0,512) maps | [512,1088) prepw3 | [1088,7360) prepw | [7360,7920) prepx.
__global__ __launch_bounds__(256) void k_prep_all(
    const float* __restrict__ in_map, short* __restrict__ om_bf,
    const float* __restrict__ w0, const float* __restrict__ w1,
    const float* __restrict__ w2, const float* __restrict__ w3,
    short* __restrict__ wb3,
    const float* __restrict__ up_w, short* __restrict__ wb,
    const float* __restrict__ dep_x, short* __restrict__ px) {
    __shared__ float s_u[20][20];
    __shared__ float s_inc[18][18];
    int blk = blockIdx.x;
    int tid = threadIdx.x;

    if (blk < 512) {
        // ---- maps ----
        int b = blk >> 6;
        int inner = blk & 63;
        int ty0 = (inner >> 3) << 4, tx0 = (inner & 7) << 4;
        const float* p = in_map + (b << 12);
        const float s = 63.0f / 127.0f;
        for (int e = tid; e < 400; e += 256) {
            int yy = e / 20, xx = e % 20;
            int gy = ty0 + yy - 2, gx = tx0 + xx - 2;
            float v = 0.0f;
            if ((unsigned)gy < 128u && (unsigned)gx < 128u) {
                float cy = gy * s, cx = gx * s;
                int iy0 = (int)cy, ix0 = (int)cx;
                float wy = cy - (float)iy0, wx = cx - (float)ix0;
                int iy1 = min(iy0 + 1, 63), ix1 = min(ix0 + 1, 63);
                float v00 = p[(iy0 << 6) + ix0], v01 = p[(iy0 << 6) + ix1];
                float v10 = p[(iy1 << 6) + ix0], v11 = p[(iy1 << 6) + ix1];
                v = (1.0f - wy) * ((1.0f - wx) * v00 + wx * v01) +
                    wy          * ((1.0f - wx) * v10 + wx * v11);
            }
            s_u[yy][xx] = v;
        }
        __syncthreads();
        for (int e = tid; e < 324; e += 256) {
            int yy = e / 18, xx = e % 18;
            int gy = ty0 + yy - 1, gx = tx0 + xx - 1;
            float val = -INFINITY;
            if ((unsigned)gy < 128u && (unsigned)gx < 128u) {
                float uc = s_u[yy + 1][xx + 1];
                float mx = -INFINITY;
                for (int dy = -1; dy <= 1; ++dy) {
                    int ny = gy + dy; if ((unsigned)ny >= 128u) continue;
                    for (int dx = -1; dx <= 1; ++dx) {
                        int nx = gx + dx; if ((unsigned)nx >= 128u) continue;
                        mx = fmaxf(mx, s_u[yy + 1 + dy][xx + 1 + dx]);
                    }
                }
                val = sigm(mx) - sigm(uc);
            }
            s_inc[yy][xx] = val;
        }
        __syncthreads();
        int row = tid >> 4, col = tid & 15;
        int gy = ty0 + row, gx = tx0 + col;
        float mx = -INFINITY;
        #pragma unroll
        for (int dy = 0; dy < 3; ++dy)
            #pragma unroll
            for (int dx = 0; dx < 3; ++dx)
                mx = fmaxf(mx, s_inc[row + dy][col + dx]);
        float uc = s_u[row + 2][col + 2];
        float mn = INFINITY;
        for (int dy = -1; dy <= 1; ++dy) {
            int ny = gy + dy; if ((unsigned)ny >= 128u) continue;
            for (int dx = -1; dx <= 1; ++dx) {
                int nx = gx + dx; if ((unsigned)nx >= 128u) continue;
                mn = fminf(mn, s_u[row + 2 + dy][col + 2 + dx]);
            }
        }
        float inc2 = sigm(1.0f - mn) - sigm(1.0f - uc);
        om_bf[(b << 14) + (gy << 7) + gx] = f2bf_s(mx + inc2);
    } else if (blk < 1088) {
        // ---- prepw3: layout [layer][cc][dx][dy][o][c] ----
        int s = (blk - 512) * 256 + tid;
        int layer = s / 36864; int r = s - layer * 36864;
        const float* w = (layer == 0) ? w0 : (layer == 1) ? w1 : (layer == 2) ? w2 : w3;
        int o = r / 576; int rem = r - o * 576;
        int c = rem / 9; int t = rem - c * 9;
        int dy = t / 3, dx = t - dy * 3;
        int cc = c >> 5, cl = c & 31;
        wb3[layer * 36864 + (((cc * 3 + dx) * 3 + dy) * 64 + o) * 32 + cl] = f2bf_s(w[r]);
    } else if (blk < 7360) {
        // ---- prepw: layout [nt][cc][dx][dy][o][c] ----
        int s = (blk - 1088) * 256 + tid;
        int O = s / 6272; int r = s - O * 6272;
        int C = r / 49;   int T = r - C * 49;
        int dy = T / 7, dx = T - dy * 7;
        int nt = O >> 6, o = O & 63;
        int cc = C >> 5, c = C & 31;
        int W = ((((nt * 4 + cc) * 7 + dx) * 7 + dy) * 64 + o) * 32 + c;
        wb[W] = f2bf_s(up_w[s]);
    } else {
        // ---- prepx: [b][cc][y' 0..69][x' 0..69][40] padded bf16 ----
        int idx = blk - 7360;
        int b = idx / 70, yp = idx - (idx / 70) * 70;
        int y = yp - 3;
        bool inY = (unsigned)y < 64u;
        for (int cc = 0; cc < 4; ++cc) {
            short* orow = px + (((long)(b * 4 + cc) * 70 + yp) * 70) * 40;
            for (int e = tid; e < 350; e += 256) {
                int p2 = e / 70, xp = e - p2 * 70;
                int xg = xp - 3;
                short8 v = (short8){0, 0, 0, 0, 0, 0, 0, 0};
                if (p2 < 4 && inY && (unsigned)xg < 64u) {
                    const float* src = dep_x + (((b * 128 + cc * 32 + p2 * 8) << 12)) + (y << 6) + xg;
                    #pragma unroll
                    for (int i = 0; i < 8; ++i) v[i] = f2bf_s(src[i << 12]);
                }
                *(short8*)&orow[xp * 40 + p2 * 8] = v;
            }
        }
    }
}

// ---------------- premultiply: xin2 = bf16(om * cur_x) ----------------
__global__ __launch_bounds__(256) void k_premult(const float* __restrict__ cur_x,
                                                 const short* __restrict__ om_bf,
                                                 short* __restrict__ xin2) {
    int e = blockIdx.x * 256 + threadIdx.x;
    int flat = e << 2;
    int pix = flat & 16383;
    int b = flat >> 20;
    f32x4 xv = *(const f32x4*)&cur_x[flat];
    short4v ov = *(const short4v*)&om_bf[(b << 14) + pix];
    short4v res;
    #pragma unroll
    for (int k = 0; k < 4; ++k) res[k] = f2bf_s(xv[k] * bfb2f(ov[k]));
    *(short4v*)&xin2[flat] = res;
}

// ---------------- up-conv 7x7 MFMA v12: ZERO-LDS direct-global A-operands ----------------
// r2-r9 evidence: 5 structural changes (LDS volume, HBM, src-pipelining, occupancy,
// single-buffer) all flat at ~124us / 36% MfmaUtil — the 2-barrier staging structure's
// documented ceiling. px (12.5MB) is L2-resident and cell-tiled so every A-fragment is
// a direct global b128 (padding makes all accesses in-bounds). v12 deletes the LDS
// stage + both barriers entirely: waves free-run as pure load+MFMA streams (lesson #7:
// don't LDS-stage L2-resident data). L2 re-read ~4.5MB/CU (~80Kcyc @56B/cyc) < MFMA
// floor (122Kcyc). Per-wave memory instructions drop 372 -> 70 per cc-slice.
__global__ __launch_bounds__(512, 4) void k_upconv_mfma(
    const short* __restrict__ px,     // [8][4][70][70][40] bf16 (padded)
    const short* __restrict__ wb,     // prepped [nt4][cc4][dx7][dy7][o64][c32]
    const float* __restrict__ cb,     // [256]
    const float* __restrict__ bnp,    // [4,256]
    short* __restrict__ dep) {        // [8,64,128,128] bf16
    int tid = threadIdx.x;
    int wave = tid >> 6, lane = tid & 63;
    int q = lane >> 4, m = lane & 15;
    int mw = wave & 3, ng = wave >> 2;
    int ty0 = (blockIdx.x >> 2) * 16;
    int tx0 = (blockIdx.x & 3) * 16;
    int nt = blockIdx.y;
    int b = blockIdx.z;
    f32x4 acc[4][2];
    #pragma unroll
    for (int i = 0; i < 4; ++i)
        #pragma unroll
        for (int j = 0; j < 2; ++j)
            acc[i][j] = (f32x4){0.f, 0.f, 0.f, 0.f};

    #pragma unroll 1
    for (int cc = 0; cc < 4; ++cc) {
        // cell (Y,X) of the padded 70x70 grid at pxcc + (Y*70+X)*40 shorts.
        // Y = ty0+mw*4+r <= 48+21 = 69, X = tx0+m+dx <= 48+21 = 69: always in-bounds.
        const short* pxcc = px + (((long)(b * 4 + cc) * 70 + ty0) * 70 + tx0) * 40;
        const short* wcc = wb + ((nt * 4 + cc) * 49) * 2048;
        #pragma unroll 1
        for (int dx = 0; dx < 7; ++dx) {
            short8 a10[10];
            #pragma unroll
            for (int r = 0; r < 10; ++r)
                a10[r] = *(const short8*)(pxcc + ((mw * 4 + r) * 70 + m + dx) * 40 + q * 8);
            const short* wdx = wcc + ((dx * 7) << 11);
            short8 wf[7];
            #pragma unroll
            for (int dy = 0; dy < 7; ++dy)
                wf[dy] = *(const short8*)(wdx + (dy << 11) + ((ng * 32 + m) << 5) + (q << 3));
            #pragma unroll
            for (int dy = 0; dy < 7; ++dy)
                #pragma unroll
                for (int i = 0; i < 4; ++i)
                    acc[i][0] = __builtin_amdgcn_mfma_f32_16x16x32_bf16(
                        a10[i + dy], wf[dy], acc[i][0], 0, 0, 0);
            #pragma unroll
            for (int dy = 0; dy < 7; ++dy)
                wf[dy] = *(const short8*)(wdx + (dy << 11) + ((ng * 32 + 16 + m) << 5) + (q << 3));
            #pragma unroll
            for (int dy = 0; dy < 7; ++dy)
                #pragma unroll
                for (int i = 0; i < 4; ++i)
                    acc[i][1] = __builtin_amdgcn_mfma_f32_16x16x32_bf16(
                        a10[i + dy], wf[dy], acc[i][1], 0, 0, 0);
        }
    }
    #pragma unroll
    for (int j = 0; j < 2; ++j) {
        int o = nt * 64 + ng * 32 + j * 16 + m;
        float g  = bnp[o],       bt = bnp[256 + o];
        float mn = bnp[512 + o], vv = bnp[768 + o];
        float scale = g * rsqrtf(vv + 1e-5f);
        float cbf = cb[o];
        int c = o >> 2, sbit = (o >> 1) & 1, tbit = o & 1;
        #pragma unroll
        for (int i = 0; i < 4; ++i) {
            int y = ty0 + mw * 4 + i;
            #pragma unroll
            for (int reg = 0; reg < 4; ++reg) {
                int xc = tx0 + q * 4 + reg;
                float val = (acc[i][j][reg] + cbf - mn) * scale + bt;
                val = fmaxf(val, 0.0f);
                dep[((b * 64 + c) << 14) + ((2 * y + sbit) << 7) + (2 * xc + tbit)] = f2bf_s(val);
            }
        }
    }
}

// ---------------- 3x3 conv 64->64 MFMA v2: 16x16 tile, merged cc, ONE barrier ----------------
template <int MODE, bool OUTBF>
__global__ __launch_bounds__(512, 4) void k_conv3m(
    const short* __restrict__ xin,
    const short* __restrict__ wl,      // [cc][dx][dy][o][c]
    const short* __restrict__ dep,
    const float* __restrict__ cb,
    const float* __restrict__ bnp,
    const float* __restrict__ beta,
    void* __restrict__ out) {
    __shared__ __attribute__((aligned(16))) short s_in[324 * 88];   // 57KB
    int tid = threadIdx.x;
    int wave = tid >> 6, lane = tid & 63;
    int q = lane >> 4, m = lane & 15;
    int mw = wave & 3, og = wave >> 2;   // 4 row-groups x 2 oc-halves
    int ty0 = (blockIdx.x >> 3) * 16;
    int tx0 = (blockIdx.x & 7) * 16;
    int b = blockIdx.z;
    f32x4 acc[4][2];
    #pragma unroll
    for (int i = 0; i < 4; ++i)
        #pragma unroll
        for (int j = 0; j < 2; ++j)
            acc[i][j] = (f32x4){0.f, 0.f, 0.f, 0.f};
    const short* xb = xin + ((long)(b * 64) << 14);
    // stage 18x18 cells x 64 ic, once. e = (cq, yy, g): 8 x 18 x 6 = 864
    for (int e = tid; e < 864; e += 512) {
        int cq = e / 108; int rem = e - cq * 108;
        int yy = rem / 6; int g = rem - yy * 6;
        int gy = ty0 + yy - 1;
        int gx0 = tx0 - 4 + (g << 2);
        short4v v[8];
        if ((unsigned)gy < 128u && (unsigned)gx0 < 128u) {
            const short* src = xb + ((cq * 8) << 14) + (gy << 7) + gx0;
            #pragma unroll
            for (int j2 = 0; j2 < 8; ++j2) v[j2] = *(const short4v*)(src + (j2 << 14));
        } else {
            #pragma unroll
            for (int j2 = 0; j2 < 8; ++j2) v[j2] = (short4v){0, 0, 0, 0};
        }
        #pragma unroll
        for (int t = 0; t < 4; ++t) {
            int xx = (g << 2) - 3 + t;
            if ((unsigned)xx < 18u) {
                short8 pk;
                #pragma unroll
                for (int j2 = 0; j2 < 8; ++j2) pk[j2] = v[j2][t];
                *(short8*)&s_in[(yy * 18 + xx) * 88 + cq * 8] = pk;
            }
        }
    }
    __syncthreads();   // the ONLY barrier
    #pragma unroll 1
    for (int cc = 0; cc < 2; ++cc) {
        #pragma unroll 1
        for (int dx = 0; dx < 3; ++dx) {
            short8 a6[6];
            #pragma unroll
            for (int r = 0; r < 6; ++r)
                a6[r] = *(const short8*)&s_in[((mw * 4 + r) * 18 + m + dx) * 88 + cc * 32 + q * 8];
            const short* wdx = wl + (((cc * 3 + dx) * 3) << 11);
            short8 wf[3];
            #pragma unroll
            for (int dy = 0; dy < 3; ++dy)
                wf[dy] = *(const short8*)(wdx + (dy << 11) + ((og * 32 + m) << 5) + (q << 3));
            #pragma unroll
            for (int dy = 0; dy < 3; ++dy)
                #pragma unroll
                for (int i = 0; i < 4; ++i)
                    acc[i][0] = __builtin_amdgcn_mfma_f32_16x16x32_bf16(
                        a6[i + dy], wf[dy], acc[i][0], 0, 0, 0);
            #pragma unroll
            for (int dy = 0; dy < 3; ++dy)
                wf[dy] = *(const short8*)(wdx + (dy << 11) + ((og * 32 + 16 + m) << 5) + (q << 3));
            #pragma unroll
            for (int dy = 0; dy < 3; ++dy)
                #pragma unroll
                for (int i = 0; i < 4; ++i)
                    acc[i][1] = __builtin_amdgcn_mfma_f32_16x16x32_bf16(
                        a6[i + dy], wf[dy], acc[i][1], 0, 0, 0);
        }
    }
    float betav = (MODE == 1) ? beta[0] : 0.0f;
    #pragma unroll
    for (int j = 0; j < 2; ++j) {
        int o = og * 32 + j * 16 + m;
        float cbf = cb[o];
        float scale = 1.0f, shift = 0.0f;
        if (MODE == 0) {
            float g  = bnp[o],       bt = bnp[64 + o];
            float mm = bnp[128 + o], vv = bnp[192 + o];
            scale = g * rsqrtf(vv + 1e-5f);
            shift = bt - mm * scale;
        }
        #pragma unroll
        for (int i = 0; i < 4; ++i) {
            int y = ty0 + mw * 4 + i;
            int base = ((b * 64 + o) << 14) + (y << 7) + tx0 + q * 4;
            float vals[4];
            if (MODE == 1) {
                short4v dv = *(const short4v*)&dep[base];
                #pragma unroll
                for (int reg = 0; reg < 4; ++reg)
                    vals[reg] = bfb2f(dv[reg]) + betav * (acc[i][j][reg] + cbf);
            } else {
                #pragma unroll
                for (int reg = 0; reg < 4; ++reg)
                    vals[reg] = fmaxf((acc[i][j][reg] + cbf) * scale + shift, 0.0f);
            }
            if (OUTBF) {
                short4v sv;
                #pragma unroll
                for (int reg = 0; reg < 4; ++reg) sv[reg] = f2bf_s(vals[reg]);
                *(short4v*)((short*)out + base) = sv;
            } else {
                f32x4 fv;
                #pragma unroll
                for (int reg = 0; reg < 4; ++reg) fv[reg] = vals[reg];
                *(f32x4*)((float*)out + base) = fv;
            }
        }
    }
}

// ---------------- final 7x7 conv (64->1): scalar-global weights + ILP-4 ----------------
__global__ __launch_bounds__(256) void k_outconv(
    const float* __restrict__ r,
    const float* __restrict__ w,
    const float* __restrict__ ob,
    float* __restrict__ out) {
    __shared__ float s_in[8][22][22];
    int tid = threadIdx.x;
    int ty = tid >> 4, tx = tid & 15;
    int ty0 = (blockIdx.x >> 3) << 4, tx0 = (blockIdx.x & 7) << 4;
    int b = blockIdx.z;
    float acc4[4] = {0.f, 0.f, 0.f, 0.f};
    for (int c0 = 0; c0 < 64; c0 += 8) {
        __syncthreads();
        for (int e = tid; e < 8 * 484; e += 256) {
            int i = e / 484; int r2 = e - i * 484; int yy = r2 / 22; int xx = r2 - yy * 22;
            int gy = ty0 + yy - 3, gx = tx0 + xx - 3;
            float v = 0.0f;
            if ((unsigned)gy < 128u && (unsigned)gx < 128u)
                v = r[((b * 64 + c0 + i) << 14) + (gy << 7) + gx];
            s_in[i][yy][xx] = v;
        }
        __syncthreads();
        for (int i = 0; i < 8; ++i) {
            const float* wrow = w + (c0 + i) * 49;
            #pragma unroll
            for (int dy = 0; dy < 7; ++dy)
                #pragma unroll
                for (int dx = 0; dx < 7; ++dx)
                    acc4[i & 3] = fmaf(s_in[i][ty + dy][tx + dx], wrow[dy * 7 + dx], acc4[i & 3]);
        }
    }
    out[(b << 14) + ((ty0 + ty) << 7) + tx0 + tx] =
        (acc4[0] + acc4[1]) + (acc4[2] + acc4[3]) + ob[0];
}

extern "C" void kernel_launch(void* const* d_in, const int* in_sizes, int n_in,
                              void* d_out, int out_size, void* d_ws, size_t ws_size,
                              hipStream_t stream) {
    const float* cur_x  = (const float*)d_in[0];
    const float* dep_x  = (const float*)d_in[1];
    const float* in_map = (const float*)d_in[2];
    const float* up_w   = (const float*)d_in[3];
    const float* up_b   = (const float*)d_in[4];
    const float* up_bn  = (const float*)d_in[5];
    const float* c2_w   = (const float*)d_in[6];
    const float* c2_b   = (const float*)d_in[7];
    const float* d1_w   = (const float*)d_in[8];
    const float* d1_b   = (const float*)d_in[9];
    const float* d1_bn  = (const float*)d_in[10];
    const float* d2_w   = (const float*)d_in[11];
    const float* d2_b   = (const float*)d_in[12];
    const float* d2_bn  = (const float*)d_in[13];
    const float* d3_w   = (const float*)d_in[14];
    const float* d3_b   = (const float*)d_in[15];
    const float* d3_bn  = (const float*)d_in[16];
    const float* out_w  = (const float*)d_in[17];
    const float* out_b  = (const float*)d_in[18];
    const float* beta   = (const float*)d_in[19];

    // Buffer plan (ws use = 16.8 MiB, proven safe):
    //   A   = ws[0..16.8M) bf16       : xin2 then r2
    //   B   = d_out[0..16.8M) bf16    : dep then r1
    //   C   = d_out[16.8..33.5M) bf16 : wb (3.21M) + px (12.54M) + om_bf (0.26M in the
    //         slack at byte 32532480) until upconv/premult done, then t (full 16.8M)
    //   wb3 = d_out[33.5M..] (0.29M)  : persists through conv3m; overwritten by mapout last
    //   r_out fp32 = d_out[0..33.5M) : final r written by d3
    char* ob = (char*)d_out;
    float* r_out  = (float*)ob;
    short* A      = (short*)d_ws;
    short* B      = (short*)ob;
    short* C      = (short*)(ob + 16777216);
    short* wb     = C;
    short* px     = wb + 1605632;            // bytes [19988480, 32532480)
    short* om_bf  = (short*)(ob + 32532480); // bytes [32532480, 32794624) — slack after px
    short* wb3    = (short*)(ob + 33554432);
    float* mapout = (float*)(ob + 33554432);

    k_prep_all<<<7920, 256, 0, stream>>>(in_map, om_bf, c2_w, d1_w, d2_w, d3_w, wb3,
                                         up_w, wb, dep_x, px);
    k_premult<<<8192, 256, 0, stream>>>(cur_x, om_bf, A);
    k_upconv_mfma<<<dim3(16, 4, 8), 512, 0, stream>>>(px, wb, up_b, up_bn, B);
    k_conv3m<1, true><<<dim3(64, 1, 8), 512, 0, stream>>>(
        A, wb3 + 0 * 36864, B, c2_b, nullptr, beta, C);
    k_conv3m<0, true><<<dim3(64, 1, 8), 512, 0, stream>>>(
        C, wb3 + 1 * 36864, nullptr, d1_b, d1_bn, nullptr, B);
    k_conv3m<0, true><<<dim3(64, 1, 8), 512, 0, stream>>>(
        B, wb3 + 2 * 36864, nullptr, d2_b, d2_bn, nullptr, A);
    k_conv3m<0, false><<<dim3(64, 1, 8), 512, 0, stream>>>(
        A, wb3 + 3 * 36864, nullptr, d3_b, d3_bn, nullptr, r_out);
    k_outconv<<<dim3(64, 1, 8), 256, 0, stream>>>(r_out, out_w, out_b, mapout);
}

// Round 11
// 426.387 us; speedup vs baseline: 1.1720x; 1.1720x over previous
//
#include <hip/hip_runtime.h>
#include <hip/hip_bf16.h>
#include <math.h>

static __device__ __forceinline__ float sigm(float x) { return 1.0f / (1.0f + expf(-x)); }

// fp32 -> bf16 bits, round-to-nearest-even
static __device__ __forceinline__ short f2bf_s(float f) {
    unsigned u = __float_as_uint(f);
    u += 0x7fffu + ((u >> 16) & 1u);
    return (short)(u >> 16);
}
// bf16 bits -> fp32
static __device__ __forceinline__ float bfb2f(short s) {
    return __uint_as_float(((unsigned)(unsigned short)s) << 16);
}

typedef __attribute__((ext_vector_type(8))) short short8;
typedef __attribute__((ext_vector_type(4))) short short4v;
typedef __attribute__((ext_vector_type(4))) float f32x4;

static __device__ __forceinline__ void gl_lds16(const void* g, void* l) {
    __builtin_amdgcn_global_load_lds(
        (const __attribute__((address_space(1))) unsigned int*)g,
        (__attribute__((address_space(3))) unsigned int*)l, 16, 0, 0);
}

// ---------------- fused prep: maps + prepw3 + prepw + prepx in one launch ----------------
// Block ranges: [0,512) maps | [512,1088) prepw3 | [1088,7360) prepw | [7360,7920) prepx.
__global__ __launch_bounds__(256) void k_prep_all(
    const float* __restrict__ in_map, short* __restrict__ om_bf,
    const float* __restrict__ w0, const float* __restrict__ w1,
    const float* __restrict__ w2, const float* __restrict__ w3,
    short* __restrict__ wb3,
    const float* __restrict__ up_w, short* __restrict__ wb,
    const float* __restrict__ dep_x, short* __restrict__ px) {
    __shared__ float s_u[20][20];
    __shared__ float s_inc[18][18];
    int blk = blockIdx.x;
    int tid = threadIdx.x;

    if (blk < 512) {
        // ---- maps ----
        int b = blk >> 6;
        int inner = blk & 63;
        int ty0 = (inner >> 3) << 4, tx0 = (inner & 7) << 4;
        const float* p = in_map + (b << 12);
        const float s = 63.0f / 127.0f;
        for (int e = tid; e < 400; e += 256) {
            int yy = e / 20, xx = e % 20;
            int gy = ty0 + yy - 2, gx = tx0 + xx - 2;
            float v = 0.0f;
            if ((unsigned)gy < 128u && (unsigned)gx < 128u) {
                float cy = gy * s, cx = gx * s;
                int iy0 = (int)cy, ix0 = (int)cx;
                float wy = cy - (float)iy0, wx = cx - (float)ix0;
                int iy1 = min(iy0 + 1, 63), ix1 = min(ix0 + 1, 63);
                float v00 = p[(iy0 << 6) + ix0], v01 = p[(iy0 << 6) + ix1];
                float v10 = p[(iy1 << 6) + ix0], v11 = p[(iy1 << 6) + ix1];
                v = (1.0f - wy) * ((1.0f - wx) * v00 + wx * v01) +
                    wy          * ((1.0f - wx) * v10 + wx * v11);
            }
            s_u[yy][xx] = v;
        }
        __syncthreads();
        for (int e = tid; e < 324; e += 256) {
            int yy = e / 18, xx = e % 18;
            int gy = ty0 + yy - 1, gx = tx0 + xx - 1;
            float val = -INFINITY;
            if ((unsigned)gy < 128u && (unsigned)gx < 128u) {
                float uc = s_u[yy + 1][xx + 1];
                float mx = -INFINITY;
                for (int dy = -1; dy <= 1; ++dy) {
                    int ny = gy + dy; if ((unsigned)ny >= 128u) continue;
                    for (int dx = -1; dx <= 1; ++dx) {
                        int nx = gx + dx; if ((unsigned)nx >= 128u) continue;
                        mx = fmaxf(mx, s_u[yy + 1 + dy][xx + 1 + dx]);
                    }
                }
                val = sigm(mx) - sigm(uc);
            }
            s_inc[yy][xx] = val;
        }
        __syncthreads();
        int row = tid >> 4, col = tid & 15;
        int gy = ty0 + row, gx = tx0 + col;
        float mx = -INFINITY;
        #pragma unroll
        for (int dy = 0; dy < 3; ++dy)
            #pragma unroll
            for (int dx = 0; dx < 3; ++dx)
                mx = fmaxf(mx, s_inc[row + dy][col + dx]);
        float uc = s_u[row + 2][col + 2];
        float mn = INFINITY;
        for (int dy = -1; dy <= 1; ++dy) {
            int ny = gy + dy; if ((unsigned)ny >= 128u) continue;
            for (int dx = -1; dx <= 1; ++dx) {
                int nx = gx + dx; if ((unsigned)nx >= 128u) continue;
                mn = fminf(mn, s_u[row + 2 + dy][col + 2 + dx]);
            }
        }
        float inc2 = sigm(1.0f - mn) - sigm(1.0f - uc);
        om_bf[(b << 14) + (gy << 7) + gx] = f2bf_s(mx + inc2);
    } else if (blk < 1088) {
        // ---- prepw3: layout [layer][cc][dx][dy][o][c] ----
        int s = (blk - 512) * 256 + tid;
        int layer = s / 36864; int r = s - layer * 36864;
        const float* w = (layer == 0) ? w0 : (layer == 1) ? w1 : (layer == 2) ? w2 : w3;
        int o = r / 576; int rem = r - o * 576;
        int c = rem / 9; int t = rem - c * 9;
        int dy = t / 3, dx = t - dy * 3;
        int cc = c >> 5, cl = c & 31;
        wb3[layer * 36864 + (((cc * 3 + dx) * 3 + dy) * 64 + o) * 32 + cl] = f2bf_s(w[r]);
    } else if (blk < 7360) {
        // ---- prepw: layout [nt][cc][dx][dy][o][c] ----
        int s = (blk - 1088) * 256 + tid;
        int O = s / 6272; int r = s - O * 6272;
        int C = r / 49;   int T = r - C * 49;
        int dy = T / 7, dx = T - dy * 7;
        int nt = O >> 6, o = O & 63;
        int cc = C >> 5, c = C & 31;
        int W = ((((nt * 4 + cc) * 7 + dx) * 7 + dy) * 64 + o) * 32 + c;
        wb[W] = f2bf_s(up_w[s]);
    } else {
        // ---- prepx: [b][cc][y' 0..69][x' 0..69][40] padded bf16 ----
        int idx = blk - 7360;
        int b = idx / 70, yp = idx - (idx / 70) * 70;
        int y = yp - 3;
        bool inY = (unsigned)y < 64u;
        for (int cc = 0; cc < 4; ++cc) {
            short* orow = px + (((long)(b * 4 + cc) * 70 + yp) * 70) * 40;
            for (int e = tid; e < 350; e += 256) {
                int p2 = e / 70, xp = e - p2 * 70;
                int xg = xp - 3;
                short8 v = (short8){0, 0, 0, 0, 0, 0, 0, 0};
                if (p2 < 4 && inY && (unsigned)xg < 64u) {
                    const float* src = dep_x + (((b * 128 + cc * 32 + p2 * 8) << 12)) + (y << 6) + xg;
                    #pragma unroll
                    for (int i = 0; i < 8; ++i) v[i] = f2bf_s(src[i << 12]);
                }
                *(short8*)&orow[xp * 40 + p2 * 8] = v;
            }
        }
    }
}

// ---------------- premultiply -> CELL layout: xcell[b][cc][y][x][32] = bf16(om*cur_x) ----------------
// Thread (x, p2) handles 16 channels of one cell: 16 strided 4B reads, 32B contiguous write.
__global__ __launch_bounds__(256) void k_premult_cell(
    const float* __restrict__ cur_x,
    const short* __restrict__ om_bf,
    short* __restrict__ xcell) {
    int y = blockIdx.x;       // 0..127
    int cc = blockIdx.y;      // 0..1
    int b = blockIdx.z;       // 0..7
    int tid = threadIdx.x;
    int x = tid >> 1, p2 = tid & 1;
    float om = bfb2f(om_bf[(b << 14) + (y << 7) + x]);
    const float* src = cur_x + (((b * 64 + cc * 32 + p2 * 16) << 14) + (y << 7) + x);
    short8 v0, v1;
    #pragma unroll
    for (int i = 0; i < 8; ++i) v0[i] = f2bf_s(src[(long)i << 14] * om);
    #pragma unroll
    for (int i = 0; i < 8; ++i) v1[i] = f2bf_s(src[(long)(8 + i) << 14] * om);
    short* dst = xcell + ((((long)(b * 2 + cc) * 128 + y) * 128 + x) << 5) + (p2 << 4);
    *(short8*)dst = v0;
    *(short8*)(dst + 8) = v1;
}

// ---------------- up-conv 7x7 MFMA (r9-proven core; epilogue now writes dep in CELL layout) ----
__global__ __launch_bounds__(512, 4) void k_upconv_mfma(
    const short* __restrict__ px,     // [8][4][70][70][40] bf16 (padded)
    const short* __restrict__ wb,     // prepped [nt4][cc4][dx7][dy7][o64][c32]
    const float* __restrict__ cb,     // [256]
    const float* __restrict__ bnp,    // [4,256]
    short* __restrict__ depc) {       // CELL layout [8][2][128][128][32] bf16
    __shared__ __attribute__((aligned(16))) short s_in[19360];
    int tid = threadIdx.x;
    int wave = tid >> 6, lane = tid & 63;
    int q = lane >> 4, m = lane & 15;
    int mw = wave & 3, ng = wave >> 2;
    int ty0 = (blockIdx.x >> 2) * 16;
    int tx0 = (blockIdx.x & 3) * 16;
    int nt = blockIdx.y;
    int b = blockIdx.z;
    f32x4 acc[4][2];
    #pragma unroll
    for (int i = 0; i < 4; ++i)
        #pragma unroll
        for (int j = 0; j < 2; ++j)
            acc[i][j] = (f32x4){0.f, 0.f, 0.f, 0.f};

    auto stage = [&](int cc) {
        const short* pxcc = px + ((((long)(b * 4 + cc) * 70 + ty0) * 70 + tx0) * 40);
        for (int c0 = (wave << 6); c0 < 2420; c0 += 512) {
            int chunk = c0 + lane;
            int row = chunk / 110;
            int k = chunk - row * 110;
            if (chunk < 2420)
                gl_lds16(pxcc + row * 2800 + (k << 3), &s_in[c0 << 3]);
        }
    };

    for (int cc = 0; cc < 4; ++cc) {
        if (cc) __syncthreads();
        stage(cc);
        __syncthreads();
        const short* sb = &s_in[0];
        const short* wcc = wb + ((nt * 4 + cc) * 49) * 2048;
        #pragma unroll 1
        for (int dx = 0; dx < 7; ++dx) {
            short8 a10[10];
            #pragma unroll
            for (int r = 0; r < 10; ++r)
                a10[r] = *(const short8*)&sb[((mw * 4 + r) * 22 + m + dx) * 40 + q * 8];
            const short* wdx = wcc + ((dx * 7) << 11);
            short8 wf[7];
            #pragma unroll
            for (int dy = 0; dy < 7; ++dy)
                wf[dy] = *(const short8*)(wdx + (dy << 11) + ((ng * 32 + m) << 5) + (q << 3));
            #pragma unroll
            for (int dy = 0; dy < 7; ++dy)
                #pragma unroll
                for (int i = 0; i < 4; ++i)
                    acc[i][0] = __builtin_amdgcn_mfma_f32_16x16x32_bf16(
                        a10[i + dy], wf[dy], acc[i][0], 0, 0, 0);
            #pragma unroll
            for (int dy = 0; dy < 7; ++dy)
                wf[dy] = *(const short8*)(wdx + (dy << 11) + ((ng * 32 + 16 + m) << 5) + (q << 3));
            #pragma unroll
            for (int dy = 0; dy < 7; ++dy)
                #pragma unroll
                for (int i = 0; i < 4; ++i)
                    acc[i][1] = __builtin_amdgcn_mfma_f32_16x16x32_bf16(
                        a10[i + dy], wf[dy], acc[i][1], 0, 0, 0);
        }
    }
    // epilogue: bias + BN + ReLU + pixel-shuffle scatter into CELL layout
    #pragma unroll
    for (int j = 0; j < 2; ++j) {
        int o = nt * 64 + ng * 32 + j * 16 + m;
        float g  = bnp[o],       bt = bnp[256 + o];
        float mn = bnp[512 + o], vv = bnp[768 + o];
        float scale = g * rsqrtf(vv + 1e-5f);
        float cbf = cb[o];
        int c = o >> 2, sbit = (o >> 1) & 1, tbit = o & 1;
        int cc2 = c >> 5, slot = c & 31;
        #pragma unroll
        for (int i = 0; i < 4; ++i) {
            int y = ty0 + mw * 4 + i;
            int Y = 2 * y + sbit;
            #pragma unroll
            for (int reg = 0; reg < 4; ++reg) {
                int xc = tx0 + q * 4 + reg;
                int X = 2 * xc + tbit;
                float val = (acc[i][j][reg] + cbf - mn) * scale + bt;
                val = fmaxf(val, 0.0f);
                depc[((((long)(b * 2 + cc2) * 128 + Y) * 128 + X) << 5) + slot] = f2bf_s(val);
            }
        }
    }
}

// ---------------- 3x3 conv 64->64 MFMA v3: CELL-layout input (coalesced staging) ----------------
// Input xcell [b][cc2][128][128][32]: staging is 2592 x 16B fully-contiguous-per-row loads
// (reg-staged; ~5/thread) replacing the 8B x 32KB-stride transpose repeated since r0.
// LDS [cc][18x18 cells][32 slots] = 41.5KB; one barrier; a6 reads are contiguous 1024B/wave.
template <int MODE, bool OUTBF>
__global__ __launch_bounds__(512, 4) void k_conv3m(
    const short* __restrict__ xcell,
    const short* __restrict__ wl,      // [cc][dx][dy][o][c]
    const short* __restrict__ depc,    // CELL layout (MODE 1 only)
    const float* __restrict__ cb,
    const float* __restrict__ bnp,
    const float* __restrict__ beta,
    void* __restrict__ out) {
    __shared__ __attribute__((aligned(16))) short s_in[20736];   // 2 x 324 x 32
    int tid = threadIdx.x;
    int wave = tid >> 6, lane = tid & 63;
    int q = lane >> 4, m = lane & 15;
    int mw = wave & 3, og = wave >> 2;   // 4 row-groups x 2 oc-halves
    int ty0 = (blockIdx.x >> 3) * 16;
    int tx0 = (blockIdx.x & 7) * 16;
    int b = blockIdx.z;
    f32x4 acc[4][2];
    #pragma unroll
    for (int i = 0; i < 4; ++i)
        #pragma unroll
        for (int j = 0; j < 2; ++j)
            acc[i][j] = (f32x4){0.f, 0.f, 0.f, 0.f};
    // stage 2592 16B chunks (cc-major, cell-major, 4 parts/cell), reg-staged with
    // per-cell zero fill at image borders.
    for (int chunk = tid; chunk < 2592; chunk += 512) {
        int cc = chunk / 1296;
        int rem = chunk - cc * 1296;
        int cell = rem >> 2, part = rem & 3;
        int Y = cell / 18, X = cell - Y * 18;
        int gy = ty0 + Y - 1, gx = tx0 + X - 1;
        short8 v = (short8){0, 0, 0, 0, 0, 0, 0, 0};
        if ((unsigned)gy < 128u && (unsigned)gx < 128u)
            v = *(const short8*)(xcell + ((((long)(b * 2 + cc) * 128 + gy) * 128 + gx) << 5) + (part << 3));
        *(short8*)&s_in[chunk << 3] = v;
    }
    __syncthreads();   // the only barrier
    #pragma unroll 1
    for (int cc = 0; cc < 2; ++cc) {
        #pragma unroll 1
        for (int dx = 0; dx < 3; ++dx) {
            short8 a6[6];
            #pragma unroll
            for (int r = 0; r < 6; ++r)
                a6[r] = *(const short8*)&s_in[((cc * 324 + (mw * 4 + r) * 18 + m + dx) << 5) + q * 8];
            const short* wdx = wl + (((cc * 3 + dx) * 3) << 11);
            short8 wf[3];
            #pragma unroll
            for (int dy = 0; dy < 3; ++dy)
                wf[dy] = *(const short8*)(wdx + (dy << 11) + ((og * 32 + m) << 5) + (q << 3));
            #pragma unroll
            for (int dy = 0; dy < 3; ++dy)
                #pragma unroll
                for (int i = 0; i < 4; ++i)
                    acc[i][0] = __builtin_amdgcn_mfma_f32_16x16x32_bf16(
                        a6[i + dy], wf[dy], acc[i][0], 0, 0, 0);
            #pragma unroll
            for (int dy = 0; dy < 3; ++dy)
                wf[dy] = *(const short8*)(wdx + (dy << 11) + ((og * 32 + 16 + m) << 5) + (q << 3));
            #pragma unroll
            for (int dy = 0; dy < 3; ++dy)
                #pragma unroll
                for (int i = 0; i < 4; ++i)
                    acc[i][1] = __builtin_amdgcn_mfma_f32_16x16x32_bf16(
                        a6[i + dy], wf[dy], acc[i][1], 0, 0, 0);
        }
    }
    float betav = (MODE == 1) ? beta[0] : 0.0f;
    #pragma unroll
    for (int j = 0; j < 2; ++j) {
        int o = og * 32 + j * 16 + m;      // channel 0..63; cc_out = og, slot = j*16+m
        float cbf = cb[o];
        float scale = 1.0f, shift = 0.0f;
        if (MODE == 0) {
            float g  = bnp[o],       bt = bnp[64 + o];
            float mm = bnp[128 + o], vv = bnp[192 + o];
            scale = g * rsqrtf(vv + 1e-5f);
            shift = bt - mm * scale;
        }
        #pragma unroll
        for (int i = 0; i < 4; ++i) {
            int y = ty0 + mw * 4 + i;
            #pragma unroll
            for (int reg = 0; reg < 4; ++reg) {
                int xpos = tx0 + q * 4 + reg;
                long caddr = ((((long)(b * 2 + og) * 128 + y) * 128 + xpos) << 5) + j * 16 + m;
                float val;
                if (MODE == 1) {
                    val = bfb2f(depc[caddr]) + betav * (acc[i][j][reg] + cbf);
                } else {
                    val = fmaxf((acc[i][j][reg] + cbf) * scale + shift, 0.0f);
                }
                if (OUTBF) {
                    ((short*)out)[caddr] = f2bf_s(val);
                } else {
                    ((float*)out)[((b * 64 + o) << 14) + (y << 7) + xpos] = val;
                }
            }
        }
    }
}

// ---------------- final 7x7 conv (64->1): scalar-global weights + ILP-4 ----------------
__global__ __launch_bounds__(256) void k_outconv(
    const float* __restrict__ r,
    const float* __restrict__ w,
    const float* __restrict__ ob,
    float* __restrict__ out) {
    __shared__ float s_in[8][22][22];
    int tid = threadIdx.x;
    int ty = tid >> 4, tx = tid & 15;
    int ty0 = (blockIdx.x >> 3) << 4, tx0 = (blockIdx.x & 7) << 4;
    int b = blockIdx.z;
    float acc4[4] = {0.f, 0.f, 0.f, 0.f};
    for (int c0 = 0; c0 < 64; c0 += 8) {
        __syncthreads();
        for (int e = tid; e < 8 * 484; e += 256) {
            int i = e / 484; int r2 = e - i * 484; int yy = r2 / 22; int xx = r2 - yy * 22;
            int gy = ty0 + yy - 3, gx = tx0 + xx - 3;
            float v = 0.0f;
            if ((unsigned)gy < 128u && (unsigned)gx < 128u)
                v = r[((b * 64 + c0 + i) << 14) + (gy << 7) + gx];
            s_in[i][yy][xx] = v;
        }
        __syncthreads();
        for (int i = 0; i < 8; ++i) {
            const float* wrow = w + (c0 + i) * 49;
            #pragma unroll
            for (int dy = 0; dy < 7; ++dy)
                #pragma unroll
                for (int dx = 0; dx < 7; ++dx)
                    acc4[i & 3] = fmaf(s_in[i][ty + dy][tx + dx], wrow[dy * 7 + dx], acc4[i & 3]);
        }
    }
    out[(b << 14) + ((ty0 + ty) << 7) + tx0 + tx] =
        (acc4[0] + acc4[1]) + (acc4[2] + acc4[3]) + ob[0];
}

extern "C" void kernel_launch(void* const* d_in, const int* in_sizes, int n_in,
                              void* d_out, int out_size, void* d_ws, size_t ws_size,
                              hipStream_t stream) {
    const float* cur_x  = (const float*)d_in[0];
    const float* dep_x  = (const float*)d_in[1];
    const float* in_map = (const float*)d_in[2];
    const float* up_w   = (const float*)d_in[3];
    const float* up_b   = (const float*)d_in[4];
    const float* up_bn  = (const float*)d_in[5];
    const float* c2_w   = (const float*)d_in[6];
    const float* c2_b   = (const float*)d_in[7];
    const float* d1_w   = (const float*)d_in[8];
    const float* d1_b   = (const float*)d_in[9];
    const float* d1_bn  = (const float*)d_in[10];
    const float* d2_w   = (const float*)d_in[11];
    const float* d2_b   = (const float*)d_in[12];
    const float* d2_bn  = (const float*)d_in[13];
    const float* d3_w   = (const float*)d_in[14];
    const float* d3_b   = (const float*)d_in[15];
    const float* d3_bn  = (const float*)d_in[16];
    const float* out_w  = (const float*)d_in[17];
    const float* out_b  = (const float*)d_in[18];
    const float* beta   = (const float*)d_in[19];

    // Buffer plan (all cell buffers are exactly 16.8 MB = same footprint as linear):
    //   A   = ws[0..16.8M)            : xin2_cell (premult out, conv1 in) then r2_cell
    //   B   = d_out[0..16.8M)         : dep_cell (upconv out, conv1 epi) then r1_cell
    //   C   = d_out[16.8..33.5M)      : wb + px + om_bf (slack) until upconv/premult done,
    //                                   then t_cell (conv1 out, conv2 in)
    //   wb3 = d_out[33.5M..]          : persists through conv chain; mapout written last
    //   r_out fp32 = d_out[0..33.5M)  : final r written by conv4 (over dead B,C)
    char* ob = (char*)d_out;
    float* r_out  = (float*)ob;
    short* A      = (short*)d_ws;
    short* B      = (short*)ob;
    short* C      = (short*)(ob + 16777216);
    short* wb     = C;
    short* px     = wb + 1605632;            // bytes [19988480, 32532480)
    short* om_bf  = (short*)(ob + 32532480); // bytes [32532480, 32794624) — slack after px
    short* wb3    = (short*)(ob + 33554432);
    float* mapout = (float*)(ob + 33554432);

    k_prep_all<<<7920, 256, 0, stream>>>(in_map, om_bf, c2_w, d1_w, d2_w, d3_w, wb3,
                                         up_w, wb, dep_x, px);
    k_premult_cell<<<dim3(128, 2, 8), 256, 0, stream>>>(cur_x, om_bf, A);
    k_upconv_mfma<<<dim3(16, 4, 8), 512, 0, stream>>>(px, wb, up_b, up_bn, B);
    k_conv3m<1, true><<<dim3(64, 1, 8), 512, 0, stream>>>(
        A, wb3 + 0 * 36864, B, c2_b, nullptr, beta, C);
    k_conv3m<0, true><<<dim3(64, 1, 8), 512, 0, stream>>>(
        C, wb3 + 1 * 36864, nullptr, d1_b, d1_bn, nullptr, B);
    k_conv3m<0, true><<<dim3(64, 1, 8), 512, 0, stream>>>(
        B, wb3 + 2 * 36864, nullptr, d2_b, d2_bn, nullptr, A);
    k_conv3m<0, false><<<dim3(64, 1, 8), 512, 0, stream>>>(
        A, wb3 + 3 * 36864, nullptr, d3_b, d3_bn, nullptr, r_out);
    k_outconv<<<dim3(64, 1, 8), 256, 0, stream>>>(r_out, out_w, out_b, mapout);
}